// Round 2
// baseline (275.817 us; speedup 1.0000x reference)
//
#include <hip/hip_runtime.h>
#include <hip/hip_bf16.h>

#define D_ 1024
#define H_ 16
#define FF_ 2048
#define B_ 8
#define S_ 1027
#define MPAD_ 8320   /* 65 * 128 */
#define EPS_ 1e-5f

typedef __hip_bfloat16 bf16;
typedef unsigned short u16;
typedef unsigned int u32;
typedef __attribute__((ext_vector_type(4))) float floatx4;
typedef __bf16 bf16x8 __attribute__((ext_vector_type(8)));

__device__ __forceinline__ float b2f(bf16 v) { return __bfloat162float(v); }

__device__ __forceinline__ float2 bfpair(u32 u) {
  union { u32 u; float f; } lo, hi;
  lo.u = u << 16; hi.u = u & 0xffff0000u;
  return make_float2(lo.f, hi.f);
}

__device__ __forceinline__ u32 f2bfbits(float f) {
  union { bf16 h; u16 u; } cv; cv.h = __float2bfloat16(f); return (u32)cv.u;
}

// dot of 8 bf16 (packed in a uint4) with 8 floats at p
__device__ __forceinline__ float dot8(const float* p, uint4 wv) {
  float2 a = bfpair(wv.x), b = bfpair(wv.y), c = bfpair(wv.z), d = bfpair(wv.w);
  return p[0]*a.x + p[1]*a.y + p[2]*b.x + p[3]*b.y +
         p[4]*c.x + p[5]*c.y + p[6]*d.x + p[7]*d.y;
}

__device__ __forceinline__ void async_copy16(const void* g, void* l) {
  __builtin_amdgcn_global_load_lds(
      (__attribute__((address_space(1))) void*)(void*)g,
      (__attribute__((address_space(3))) void*)l, 16, 0, 0);
}

__device__ __forceinline__ float block_sum(float x, float* red) {
  const int t = threadIdx.x;
  __syncthreads();
  red[t] = x;
  __syncthreads();
  for (int s = 128; s > 0; s >>= 1) {
    if (t < s) red[t] += red[t + s];
    __syncthreads();
  }
  return red[0];
}

__device__ __forceinline__ float block_max(float x, float* red) {
  const int t = threadIdx.x;
  __syncthreads();
  red[t] = x;
  __syncthreads();
  for (int s = 128; s > 0; s >>= 1) {
    if (t < s) red[t] = fmaxf(red[t], red[t + s]);
    __syncthreads();
  }
  return red[0];
}

// ---------------------------------------------------------------------------
// Kernel 1: build merged sequence as bf16, zero rows for invalid positions.
// One block per row (MPAD_ rows), 256 threads x 4 elements each. f32 in.
// ---------------------------------------------------------------------------
__global__ void __launch_bounds__(256) build_seq_kernel(
    const float* __restrict__ x, const float* __restrict__ y,
    const float* __restrict__ cls, const float* __restrict__ sep,
    const float* __restrict__ px, const float* __restrict__ py,
    const int* __restrict__ x_len, const int* __restrict__ y_len,
    bf16* __restrict__ seq) {
  const int m = blockIdx.x, t = threadIdx.x;
  uint2* orow = (uint2*)(seq + (size_t)m * D_);
  const int b = m / S_;
  const int s = m - b * S_;
  const float* src = nullptr;
  const float* add = nullptr;
  if (b < B_) {
    const int lx = x_len[b], ly = y_len[b];
    if (s == 0) src = cls;
    else if (s <= lx) { src = x + ((size_t)b * 512 + (s - 1)) * D_; add = px; }
    else if (s == lx + 1) src = sep;
    else if (s <= lx + ly + 1) { src = y + ((size_t)b * 512 + (s - lx - 2)) * D_; add = py; }
    else if (s == lx + ly + 2) src = sep;
  }
  if (!src) { orow[t] = make_uint2(0u, 0u); return; }
  float4 sv = ((const float4*)src)[t];
  if (add) {
    float4 av = ((const float4*)add)[t];
    sv.x += av.x; sv.y += av.y; sv.z += av.z; sv.w += av.w;
  }
  uint2 o;
  o.x = f2bfbits(sv.x) | (f2bfbits(sv.y) << 16);
  o.y = f2bfbits(sv.z) | (f2bfbits(sv.w) << 16);
  orow[t] = o;
}

// ---------------------------------------------------------------------------
// Kernel 1b: convert the K/V half of Wqkv (rows 1024..3071, f32) to bf16.
// Flat: 2048*1024 elements, 4 per thread.
// ---------------------------------------------------------------------------
__global__ void __launch_bounds__(256) cvt_wkv_kernel(
    const float* __restrict__ src, bf16* __restrict__ dst) {
  const int i = blockIdx.x * 256 + threadIdx.x;
  float4 v = ((const float4*)src)[i];
  uint2 o;
  o.x = f2bfbits(v.x) | (f2bfbits(v.y) << 16);
  o.y = f2bfbits(v.z) | (f2bfbits(v.w) << 16);
  ((uint2*)dst)[i] = o;
}

// ---------------------------------------------------------------------------
// Kernel 2: KV projection GEMM. KV[m, n] = sum_k seq[m,k] * Wkv[n, k]
// + bqkv[1024+n], stored bf16 into KV[MPAD_][2048].
// 128x128 tile, BK=32, mfma_f32_16x16x32_bf16, global_load_lds width 16.
// Early-exit for M-tiles with no valid (unmasked) rows.
// ---------------------------------------------------------------------------
__global__ void __launch_bounds__(256) kv_gemm_kernel(
    const bf16* __restrict__ seq, const bf16* __restrict__ Wkv,
    const float* __restrict__ bqkv, const int* __restrict__ x_len,
    const int* __restrict__ y_len, bf16* __restrict__ KV) {
  const int nt = blockIdx.x, mt = blockIdx.y;
  const int m0 = mt * 128, n0 = nt * 128;
  bool valid = false;
#pragma unroll
  for (int b = 0; b < B_; ++b) {
    int rs = b * S_;
    int re = rs + x_len[b] + y_len[b] + 3;   // valid rows [rs, re)
    if (m0 < re && m0 + 128 > rs) valid = true;
  }
  if (!valid) return;  // masked keys get softmax weight exactly 0 -> skip

  __shared__ u16 Als[128 * 32];
  __shared__ u16 Bls[128 * 32];

  const int t = threadIdx.x;
  const int lane = t & 63, w = t >> 6;
  const int lane16 = lane & 15, quad = lane >> 4;
  const int m_off = (w & 1) * 64, n_off = (w >> 1) * 64;

  const char* Ab = (const char*)seq + (size_t)m0 * 2048;
  const char* Bb = (const char*)Wkv + (size_t)n0 * 2048;
  const int lrow = lane >> 2;
  const int lcol = (lane & 3) * 16;

  floatx4 acc[4][4] = {};

  for (int kt = 0; kt < 32; ++kt) {
    __syncthreads();
    const int kb = kt * 64;
#pragma unroll
    for (int tt = 0; tt < 2; ++tt) {
      const int c = w * 2 + tt;
      const int row = c * 16 + lrow;
      async_copy16(Ab + (size_t)row * 2048 + kb + lcol, &Als[c * 512]);
      async_copy16(Bb + (size_t)row * 2048 + kb + lcol, &Bls[c * 512]);
    }
    __syncthreads();
    bf16x8 af[4], bfr[4];
#pragma unroll
    for (int i = 0; i < 4; ++i)
      af[i] = *(const bf16x8*)&Als[(m_off + i * 16 + lane16) * 32 + quad * 8];
#pragma unroll
    for (int j = 0; j < 4; ++j)
      bfr[j] = *(const bf16x8*)&Bls[(n_off + j * 16 + lane16) * 32 + quad * 8];
#pragma unroll
    for (int i = 0; i < 4; ++i)
#pragma unroll
      for (int j = 0; j < 4; ++j)
        acc[i][j] = __builtin_amdgcn_mfma_f32_16x16x32_bf16(af[i], bfr[j], acc[i][j], 0, 0, 0);
  }

#pragma unroll
  for (int j = 0; j < 4; ++j) {
    const int col = n0 + n_off + j * 16 + lane16;
    const float bias = bqkv[1024 + col];
#pragma unroll
    for (int i = 0; i < 4; ++i) {
      const int rbase = m0 + m_off + i * 16 + quad * 4;
#pragma unroll
      for (int r = 0; r < 4; ++r)
        KV[(size_t)(rbase + r) * 2048 + col] = __float2bfloat16(acc[i][j][r] + bias);
    }
  }
}

// ---------------------------------------------------------------------------
// Kernel 3: attention for query row 0 only. One block per (head, batch).
// Computes q0 (= cls @ Wq^T + bq, batch-independent) in-block from f32 Wqkv.
// ---------------------------------------------------------------------------
__global__ void __launch_bounds__(256) attn_kernel(
    const float* __restrict__ cls, const float* __restrict__ Wqkv,
    const float* __restrict__ bqkv, const bf16* __restrict__ KV,
    const int* __restrict__ x_len, const int* __restrict__ y_len,
    float* __restrict__ o0) {
  const int h = blockIdx.x, b = blockIdx.y;
  const int t = threadIdx.x;
  const int n = x_len[b] + y_len[b] + 3;  // valid sequence length

  __shared__ float qh[64];
  __shared__ float sc[S_];
  __shared__ float part[4][64];
  __shared__ float red[256];

  const int dd = t & 63, c = t >> 6;
  {
    const float4* wr = (const float4*)(Wqkv + (size_t)(h * 64 + dd) * 1024 + c * 256);
    const float4* cl = (const float4*)(cls + c * 256);
    float acc = 0.f;
#pragma unroll 8
    for (int i = 0; i < 64; ++i) {
      float4 wv = wr[i], cv = cl[i];
      acc += wv.x * cv.x + wv.y * cv.y + wv.z * cv.z + wv.w * cv.w;
    }
    part[c][dd] = acc;
  }
  __syncthreads();
  if (t < 64)
    qh[t] = (part[0][t] + part[1][t] + part[2][t] + part[3][t] + bqkv[h * 64 + t]) * 0.125f;
  __syncthreads();

  // scores for valid keys
  float lmax = -3.0e38f;
  for (int k = t; k < n; k += 256) {
    const uint4* kp = (const uint4*)(KV + (size_t)(b * S_ + k) * 2048 + h * 64);
    float s = 0.f;
#pragma unroll
    for (int i = 0; i < 8; ++i) s += dot8(&qh[i * 8], kp[i]);
    sc[k] = s;
    lmax = fmaxf(lmax, s);
  }
  const float gmax = block_max(lmax, red);
  float lsum = 0.f;
  for (int k = t; k < n; k += 256) {
    float p = __expf(sc[k] - gmax);
    sc[k] = p;
    lsum += p;
  }
  const float inv = 1.0f / block_sum(lsum, red);

  // P @ V
  {
    float acc = 0.f;
    for (int k = c; k < n; k += 4)
      acc += sc[k] * b2f(KV[(size_t)(b * S_ + k) * 2048 + 1024 + h * 64 + dd]);
    part[c][dd] = acc;
  }
  __syncthreads();
  if (t < 64)
    o0[b * 1024 + h * 64 + t] = (part[0][t] + part[1][t] + part[2][t] + part[3][t]) * inv;
}

// ---------------------------------------------------------------------------
// Small row-GEMM (f32 weights): out[b,d] = in[b,:] . W[d,:] + bias[d] (opt ReLU)
// Grid (N/64, B). 256 threads = 64 outputs x 4 K-chunks.
// ---------------------------------------------------------------------------
template <int K, bool RELU>
__global__ void __launch_bounds__(256) rowgemm_kernel(
    const float* __restrict__ in, const float* __restrict__ W,
    const float* __restrict__ bias, float* __restrict__ out, int N) {
  const int b = blockIdx.y, t = threadIdx.x;
  __shared__ float ls[K];
  __shared__ float part[256];
  for (int i = t; i < K; i += 256) ls[i] = in[b * K + i];
  __syncthreads();
  const int dd = t >> 2, c = t & 3;
  const int d = blockIdx.x * 64 + dd;
  const float4* wr = (const float4*)(W + (size_t)d * K + c * (K / 4));
  const float* lc = ls + c * (K / 4);
  float acc = 0.f;
#pragma unroll 8
  for (int k = 0; k < K / 16; ++k) {
    float4 wv = wr[k];
    acc += lc[k * 4] * wv.x + lc[k * 4 + 1] * wv.y +
           lc[k * 4 + 2] * wv.z + lc[k * 4 + 3] * wv.w;
  }
  part[t] = acc;
  __syncthreads();
  if (t < 64) {
    const int d2 = blockIdx.x * 64 + t;
    float vv = part[t * 4] + part[t * 4 + 1] + part[t * 4 + 2] + part[t * 4 + 3] + bias[d2];
    if (RELU) vv = fmaxf(vv, 0.f);
    out[b * N + d2] = vv;
  }
}

// ---------------------------------------------------------------------------
// LayerNorm over D=1024. SECOND=false: v = cls + a (residual 1) -> f32 h0.
// SECOND=true: v = a + bvec (h0 + FFN) -> f32 final output.
// ---------------------------------------------------------------------------
template <bool SECOND>
__global__ void __launch_bounds__(256) ln_kernel(
    const float* __restrict__ cls, const float* __restrict__ a,
    const float* __restrict__ bvec, const float* __restrict__ g,
    const float* __restrict__ be, float* __restrict__ out) {
  const int b = blockIdx.x, t = threadIdx.x;
  __shared__ float v[D_];
  __shared__ float red[256];
  for (int i = t; i < D_; i += 256) {
    float val;
    if (SECOND) val = a[b * D_ + i] + bvec[b * D_ + i];
    else        val = cls[i] + a[b * D_ + i];
    v[i] = val;
  }
  __syncthreads();
  float ls = 0.f;
  for (int i = t; i < D_; i += 256) ls += v[i];
  const float mean = block_sum(ls, red) * (1.f / D_);
  float lv = 0.f;
  for (int i = t; i < D_; i += 256) { float dk = v[i] - mean; lv += dk * dk; }
  const float var = block_sum(lv, red) * (1.f / D_);
  const float rs = rsqrtf(var + EPS_);
  for (int i = t; i < D_; i += 256)
    out[b * D_ + i] = (v[i] - mean) * rs * g[i] + be[i];
}

// ---------------------------------------------------------------------------
extern "C" void kernel_launch(void* const* d_in, const int* in_sizes, int n_in,
                              void* d_out, int out_size, void* d_ws, size_t ws_size,
                              hipStream_t stream) {
  (void)in_sizes; (void)n_in; (void)out_size; (void)ws_size;
  const float* x    = (const float*)d_in[0];
  const float* y    = (const float*)d_in[1];
  const float* cls  = (const float*)d_in[2];
  const float* sep  = (const float*)d_in[3];
  const float* px   = (const float*)d_in[4];
  const float* py   = (const float*)d_in[5];
  const float* Wqkv = (const float*)d_in[6];
  const float* bqkv = (const float*)d_in[7];
  const float* Wo   = (const float*)d_in[8];
  const float* bo   = (const float*)d_in[9];
  const float* W1   = (const float*)d_in[10];
  const float* b1   = (const float*)d_in[11];
  const float* W2   = (const float*)d_in[12];
  const float* b2   = (const float*)d_in[13];
  const float* g1   = (const float*)d_in[14];
  const float* be1  = (const float*)d_in[15];
  const float* g2   = (const float*)d_in[16];
  const float* be2  = (const float*)d_in[17];
  const int* xl     = (const int*)d_in[18];
  const int* yl     = (const int*)d_in[19];

  char* ws = (char*)d_ws;
  bf16* seq   = (bf16*)ws;                          // 8320*1024*2 = 17,039,360
  bf16* Wkv_b = (bf16*)(ws + 17039360);             // 2048*1024*2 =  4,194,304
  bf16* KV    = (bf16*)(ws + 21233664);             // 8320*2048*2 = 34,078,720
  float* o0   = (float*)(ws + 55312384);            // 8*1024*4
  float* att  = (float*)(ws + 55345152);            // 8*1024*4
  float* h0   = (float*)(ws + 55377920);            // 8*1024*4
  float* f1   = (float*)(ws + 55410688);            // 8*2048*4
  float* f2   = (float*)(ws + 55476224);            // 8*1024*4

  build_seq_kernel<<<MPAD_, 256, 0, stream>>>(x, y, cls, sep, px, py, xl, yl, seq);
  cvt_wkv_kernel<<<2048, 256, 0, stream>>>(Wqkv + 1024 * 1024, Wkv_b);
  kv_gemm_kernel<<<dim3(16, 65), 256, 0, stream>>>(seq, Wkv_b, bqkv, xl, yl, KV);
  attn_kernel<<<dim3(H_, B_), 256, 0, stream>>>(cls, Wqkv, bqkv, KV, xl, yl, o0);
  rowgemm_kernel<1024, false><<<dim3(16, B_), 256, 0, stream>>>(o0, Wo, bo, att, 1024);
  ln_kernel<false><<<B_, 256, 0, stream>>>(cls, att, nullptr, g1, be1, h0);
  rowgemm_kernel<1024, true><<<dim3(32, B_), 256, 0, stream>>>(h0, W1, b1, f1, 2048);
  rowgemm_kernel<2048, false><<<dim3(16, B_), 256, 0, stream>>>(f1, W2, b2, f2, 1024);
  ln_kernel<true><<<B_, 256, 0, stream>>>(nullptr, h0, f2, g2, be2, (float*)d_out);
}

// Round 3
// 194.519 us; speedup vs baseline: 1.4179x; 1.4179x over previous
//
#include <hip/hip_runtime.h>
#include <hip/hip_bf16.h>

#define D_ 1024
#define H_ 16
#define FF_ 2048
#define B_ 8
#define S_ 1027
#define MPAD_ 8320   /* 130 * 64 */
#define PSTR_ 1056   /* padded key stride for P (mult 32, covers 1027->1056) */
#define EPS_ 1e-5f

typedef __hip_bfloat16 bf16;
typedef unsigned short u16;
typedef unsigned int u32;
typedef __attribute__((ext_vector_type(4))) float floatx4;
typedef __bf16 bf16x8 __attribute__((ext_vector_type(8)));

__device__ __forceinline__ float2 bfpair(u32 u) {
  union { u32 u; float f; } lo, hi;
  lo.u = u << 16; hi.u = u & 0xffff0000u;
  return make_float2(lo.f, hi.f);
}

__device__ __forceinline__ u32 f2bfbits(float f) {
  union { bf16 h; u16 u; } cv; cv.h = __float2bfloat16(f); return (u32)cv.u;
}

__device__ __forceinline__ float block_sum(float x, float* red) {
  const int t = threadIdx.x;
  __syncthreads();
  red[t] = x;
  __syncthreads();
  for (int s = 128; s > 0; s >>= 1) {
    if (t < s) red[t] += red[t + s];
    __syncthreads();
  }
  return red[0];
}

__device__ __forceinline__ float block_max(float x, float* red) {
  const int t = threadIdx.x;
  __syncthreads();
  red[t] = x;
  __syncthreads();
  for (int s = 128; s > 0; s >>= 1) {
    if (t < s) red[t] = fmaxf(red[t], red[t + s]);
    __syncthreads();
  }
  return red[0];
}

// ---------------------------------------------------------------------------
// K1: build merged sequence as bf16. Invalid rows are NOT written (never read).
// ---------------------------------------------------------------------------
__global__ void __launch_bounds__(256) build_seq_kernel(
    const float* __restrict__ x, const float* __restrict__ y,
    const float* __restrict__ cls, const float* __restrict__ sep,
    const float* __restrict__ px, const float* __restrict__ py,
    const int* __restrict__ x_len, const int* __restrict__ y_len,
    bf16* __restrict__ seq) {
  const int m = blockIdx.x, t = threadIdx.x;
  const int b = m / S_;
  const int s = m - b * S_;
  if (b >= B_) return;
  const float* src = nullptr;
  const float* add = nullptr;
  const int lx = x_len[b], ly = y_len[b];
  if (s == 0) src = cls;
  else if (s <= lx) { src = x + ((size_t)b * 512 + (s - 1)) * D_; add = px; }
  else if (s == lx + 1) src = sep;
  else if (s <= lx + ly + 1) { src = y + ((size_t)b * 512 + (s - lx - 2)) * D_; add = py; }
  else if (s == lx + ly + 2) src = sep;
  if (!src) return;
  float4 sv = ((const float4*)src)[t];
  if (add) {
    float4 av = ((const float4*)add)[t];
    sv.x += av.x; sv.y += av.y; sv.z += av.z; sv.w += av.w;
  }
  uint2 o;
  o.x = f2bfbits(sv.x) | (f2bfbits(sv.y) << 16);
  o.y = f2bfbits(sv.z) | (f2bfbits(sv.w) << 16);
  ((uint2*)(seq + (size_t)m * D_))[t] = o;
}

// ---------------------------------------------------------------------------
// K2: q0s[r] = (Wq[r,:].cls + bq[r]) / 8.  Grid 256 blocks, wave per row.
// ---------------------------------------------------------------------------
__global__ void __launch_bounds__(256) qproj_kernel(
    const float* __restrict__ cls, const float* __restrict__ Wqkv,
    const float* __restrict__ bqkv, float* __restrict__ q0s) {
  __shared__ float cl[D_];
  const int t = threadIdx.x;
  *(float4*)&cl[t * 4] = ((const float4*)cls)[t];
  __syncthreads();
  const int w = t >> 6, l = t & 63;
  const int r = blockIdx.x * 4 + w;
  float acc = 0.f;
#pragma unroll
  for (int ch = 0; ch < 4; ++ch) {
    float4 wv = *(const float4*)(Wqkv + (size_t)r * D_ + ch * 256 + l * 4);
    const float* c4 = &cl[ch * 256 + l * 4];
    acc += wv.x * c4[0] + wv.y * c4[1] + wv.z * c4[2] + wv.w * c4[3];
  }
#pragma unroll
  for (int off = 32; off > 0; off >>= 1) acc += __shfl_down(acc, off, 64);
  if (l == 0) q0s[r] = (acc + bqkv[r]) * 0.125f;
}

// ---------------------------------------------------------------------------
// K3: R[d][h] = sum_e Wk[h*64+e][d] * q0s[h*64+e], split to bf16 hi/lo.
// RT_hi/RT_lo layout [16][1024]. Grid (4 colchunks, 16 heads).
// ---------------------------------------------------------------------------
__global__ void __launch_bounds__(256) rproj_kernel(
    const float* __restrict__ Wqkv, const float* __restrict__ q0s,
    u16* __restrict__ RT_hi, u16* __restrict__ RT_lo) {
  const int h = blockIdx.y, cc = blockIdx.x, t = threadIdx.x;
  __shared__ float qs[64];
  if (t < 64) qs[t] = q0s[h * 64 + t];
  __syncthreads();
  const int c = cc * 256 + t;
  const float* Wk = Wqkv + (size_t)(D_ + h * 64) * D_ + c;
  float acc = 0.f;
#pragma unroll 8
  for (int e = 0; e < 64; ++e) acc += Wk[(size_t)e * D_] * qs[e];
  const u32 hb = f2bfbits(acc);
  union { u32 u; float f; } hv; hv.u = hb << 16;
  RT_hi[h * D_ + c] = (u16)hb;
  RT_lo[h * D_ + c] = (u16)f2bfbits(acc - hv.f);
}

// ---------------------------------------------------------------------------
// K4: scores S[h][m] = seq[m,:] . R[:,h]  via MFMA 16x16x32 (hi+lo).
// Grid 130 blocks x 4 waves x 16 rows. Early-exit fully-invalid tiles.
// ---------------------------------------------------------------------------
__global__ void __launch_bounds__(256) scores_kernel(
    const bf16* __restrict__ seq, const u16* __restrict__ RT_hi,
    const u16* __restrict__ RT_lo, const int* __restrict__ x_len,
    const int* __restrict__ y_len, float* __restrict__ S) {
  const int m0 = blockIdx.x * 64;
  bool valid = false;
#pragma unroll
  for (int b = 0; b < B_; ++b) {
    int rs = b * S_, re = rs + x_len[b] + y_len[b] + 3;
    if (m0 < re && m0 + 64 > rs) valid = true;
  }
  if (!valid) return;
  const int t = threadIdx.x;
  const int w = t >> 6, lane = t & 63, lane16 = lane & 15, quad = lane >> 4;
  const int row = m0 + w * 16 + lane16;
  const u16* arow = (const u16*)seq + (size_t)row * D_ + quad * 8;
  const u16* bh = RT_hi + lane16 * D_ + quad * 8;
  const u16* bl = RT_lo + lane16 * D_ + quad * 8;
  floatx4 acc = {};
#pragma unroll 4
  for (int kt = 0; kt < 32; ++kt) {
    bf16x8 a  = *(const bf16x8*)(arow + kt * 32);
    bf16x8 vh = *(const bf16x8*)(bh + kt * 32);
    bf16x8 vl = *(const bf16x8*)(bl + kt * 32);
    acc = __builtin_amdgcn_mfma_f32_16x16x32_bf16(a, vh, acc, 0, 0, 0);
    acc = __builtin_amdgcn_mfma_f32_16x16x32_bf16(a, vl, acc, 0, 0, 0);
  }
  *(floatx4*)&S[(size_t)lane16 * MPAD_ + m0 + w * 16 + quad * 4] = acc;
}

// ---------------------------------------------------------------------------
// K5: softmax per (h, b) over valid keys; writes normalized p as bf16 into
// P[(h*8+b)*PSTR_ + k], zero-padded to PSTR_.
// ---------------------------------------------------------------------------
__global__ void __launch_bounds__(256) softmax_kernel(
    const float* __restrict__ S, const int* __restrict__ x_len,
    const int* __restrict__ y_len, u16* __restrict__ P) {
  const int h = blockIdx.x, b = blockIdx.y, t = threadIdx.x;
  const int n = x_len[b] + y_len[b] + 3;
  __shared__ float sc[PSTR_];
  __shared__ float red[256];
  const float* Sp = S + (size_t)h * MPAD_ + b * S_;
  float lmax = -3.0e38f;
  for (int k = t; k < n; k += 256) {
    float s = Sp[k];
    sc[k] = s;
    lmax = fmaxf(lmax, s);
  }
  const float gmax = block_max(lmax, red);
  float lsum = 0.f;
  for (int k = t; k < n; k += 256) {
    float p = __expf(sc[k] - gmax);
    sc[k] = p;
    lsum += p;
  }
  const float inv = 1.0f / block_sum(lsum, red);
  u16* Pp = P + (size_t)(h * 8 + b) * PSTR_;
  for (int k = t; k < PSTR_; k += 256)
    Pp[k] = (k < n) ? (u16)f2bfbits(sc[k] * inv) : (u16)0;
}

// ---------------------------------------------------------------------------
// K6: cbar[b][h][c] = sum_k p[h][k] * seq[bS+k][c]  via MFMA (M=16 heads).
// Grid (16 coltiles x 8 b); block = 4 waves x 16 cols; K-loop tiles of 32.
// ---------------------------------------------------------------------------
__global__ void __launch_bounds__(256) cbar_kernel(
    const bf16* __restrict__ seq, const u16* __restrict__ P,
    const int* __restrict__ x_len, const int* __restrict__ y_len,
    float* __restrict__ cbar) {
  const int ct = blockIdx.x, b = blockIdx.y, t = threadIdx.x;
  const int c0 = ct * 64;
  const int n = x_len[b] + y_len[b] + 3;
  const int nkt = (n + 31) >> 5;
  __shared__ u16 tile[32 * 68];
  const int w = t >> 6, lane = t & 63, lane16 = lane & 15, quad = lane >> 4;
  const int sk = t >> 3, scg = (t & 7) * 8;   // staging: key row, col group
  floatx4 acc = {};
  for (int kt = 0; kt < nkt; ++kt) {
    const int k0 = kt * 32;
    __syncthreads();
    uint4 v = make_uint4(0u, 0u, 0u, 0u);
    if (k0 + sk < n)
      v = *(const uint4*)((const u16*)seq + (size_t)(b * S_ + k0 + sk) * D_ + c0 + scg);
    *(uint2*)&tile[sk * 68 + scg]     = make_uint2(v.x, v.y);
    *(uint2*)&tile[sk * 68 + scg + 4] = make_uint2(v.z, v.w);
    __syncthreads();
    bf16x8 a = *(const bf16x8*)(P + (size_t)(lane16 * 8 + b) * PSTR_ + k0 + quad * 8);
    union { bf16x8 v; u16 u[8]; } bu;
#pragma unroll
    for (int j = 0; j < 8; ++j)
      bu.u[j] = tile[(quad * 8 + j) * 68 + w * 16 + lane16];
    acc = __builtin_amdgcn_mfma_f32_16x16x32_bf16(a, bu.v, acc, 0, 0, 0);
  }
#pragma unroll
  for (int r = 0; r < 4; ++r)
    cbar[(size_t)(b * 16 + quad * 4 + r) * D_ + c0 + w * 16 + lane16] = acc[r];
}

// ---------------------------------------------------------------------------
// Generic 8-batch GEMV: out[b][r] = in[b][:] . W[r][:] + bias[r].
// Block = 4 waves, wave per W-row; W read once (coalesced), 8 batches reused
// from LDS. PERHEAD offsets input by (row/64)*1024 (for cbar).
// ---------------------------------------------------------------------------
template <int K, int N, int BSTR, bool INBF, bool OUTBF, bool RELU, bool PERHEAD>
__global__ void __launch_bounds__(256) gemv8_kernel(
    const void* __restrict__ in_, const float* __restrict__ W,
    const float* __restrict__ bias, void* __restrict__ out_) {
  const int t = threadIdx.x;
  const int hoff = PERHEAD ? ((blockIdx.x * 4) >> 6) * D_ : 0;
  __shared__ u16 lsb[INBF ? 8 * K : 1];
  __shared__ float lsf[INBF ? 1 : 8 * K];
  // stage in[8][K] to LDS, 16B per thread per iter
  if (INBF) {
    const u16* in = (const u16*)in_;
    const int per = 8 * K / (256 * 8);
#pragma unroll
    for (int i = 0; i < per; ++i) {
      int flat = (t + i * 256) * 8;
      int b = flat / K, k = flat % K;
      *(uint4*)&lsb[flat] = *(const uint4*)(in + (size_t)b * BSTR + hoff + k);
    }
  } else {
    const float* in = (const float*)in_;
    const int per = 8 * K / (256 * 4);
#pragma unroll
    for (int i = 0; i < per; ++i) {
      int flat = (t + i * 256) * 4;
      int b = flat / K, k = flat % K;
      *(float4*)&lsf[flat] = *(const float4*)(in + (size_t)b * BSTR + hoff + k);
    }
  }
  __syncthreads();
  const int w = t >> 6, l = t & 63;
  const int r = blockIdx.x * 4 + w;
  float acc[8] = {};
#pragma unroll
  for (int ch = 0; ch < K / 256; ++ch) {
    float4 wv = *(const float4*)(W + (size_t)r * K + ch * 256 + l * 4);
#pragma unroll
    for (int b = 0; b < 8; ++b) {
      float i0, i1, i2, i3;
      if (INBF) {
        uint2 u = *(const uint2*)&lsb[b * K + ch * 256 + l * 4];
        float2 p0 = bfpair(u.x), p1 = bfpair(u.y);
        i0 = p0.x; i1 = p0.y; i2 = p1.x; i3 = p1.y;
      } else {
        const float* p = &lsf[b * K + ch * 256 + l * 4];
        i0 = p[0]; i1 = p[1]; i2 = p[2]; i3 = p[3];
      }
      acc[b] += wv.x * i0 + wv.y * i1 + wv.z * i2 + wv.w * i3;
    }
  }
#pragma unroll
  for (int off = 32; off > 0; off >>= 1)
#pragma unroll
    for (int b = 0; b < 8; ++b) acc[b] += __shfl_down(acc[b], off, 64);
  if (l == 0) {
    const float bs = bias[r];
#pragma unroll
    for (int b = 0; b < 8; ++b) {
      float v = acc[b] + bs;
      if (RELU) v = fmaxf(v, 0.f);
      if (OUTBF) ((bf16*)out_)[(size_t)b * N + r] = __float2bfloat16(v);
      else       ((float*)out_)[(size_t)b * N + r] = v;
    }
  }
}

// ---------------------------------------------------------------------------
// LayerNorm over D=1024. SECOND=false: v = cls + a -> f32 h0.
// SECOND=true: v = a + bvec -> f32 final output.
// ---------------------------------------------------------------------------
template <bool SECOND>
__global__ void __launch_bounds__(256) ln_kernel(
    const float* __restrict__ cls, const float* __restrict__ a,
    const float* __restrict__ bvec, const float* __restrict__ g,
    const float* __restrict__ be, float* __restrict__ out) {
  const int b = blockIdx.x, t = threadIdx.x;
  __shared__ float v[D_];
  __shared__ float red[256];
  for (int i = t; i < D_; i += 256) {
    float val;
    if (SECOND) val = a[b * D_ + i] + bvec[b * D_ + i];
    else        val = cls[i] + a[b * D_ + i];
    v[i] = val;
  }
  __syncthreads();
  float ls = 0.f;
  for (int i = t; i < D_; i += 256) ls += v[i];
  const float mean = block_sum(ls, red) * (1.f / D_);
  float lv = 0.f;
  for (int i = t; i < D_; i += 256) { float dk = v[i] - mean; lv += dk * dk; }
  const float var = block_sum(lv, red) * (1.f / D_);
  const float rs = rsqrtf(var + EPS_);
  for (int i = t; i < D_; i += 256)
    out[b * D_ + i] = (v[i] - mean) * rs * g[i] + be[i];
}

// ---------------------------------------------------------------------------
extern "C" void kernel_launch(void* const* d_in, const int* in_sizes, int n_in,
                              void* d_out, int out_size, void* d_ws, size_t ws_size,
                              hipStream_t stream) {
  (void)in_sizes; (void)n_in; (void)out_size; (void)ws_size;
  const float* x    = (const float*)d_in[0];
  const float* y    = (const float*)d_in[1];
  const float* cls  = (const float*)d_in[2];
  const float* sep  = (const float*)d_in[3];
  const float* px   = (const float*)d_in[4];
  const float* py   = (const float*)d_in[5];
  const float* Wqkv = (const float*)d_in[6];
  const float* bqkv = (const float*)d_in[7];
  const float* Wo   = (const float*)d_in[8];
  const float* bo   = (const float*)d_in[9];
  const float* W1   = (const float*)d_in[10];
  const float* b1   = (const float*)d_in[11];
  const float* W2   = (const float*)d_in[12];
  const float* b2   = (const float*)d_in[13];
  const float* g1   = (const float*)d_in[14];
  const float* be1  = (const float*)d_in[15];
  const float* g2   = (const float*)d_in[16];
  const float* be2  = (const float*)d_in[17];
  const int* xl     = (const int*)d_in[18];
  const int* yl     = (const int*)d_in[19];

  char* ws = (char*)d_ws;
  bf16*  seq   = (bf16*)(ws);                      // 17,039,360
  float* q0s   = (float*)(ws + 17039360);          // 4,096
  u16*   RT_hi = (u16*)(ws + 17043456);            // 32,768
  u16*   RT_lo = (u16*)(ws + 17076224);            // 32,768
  float* S     = (float*)(ws + 17108992);          // 532,480
  u16*   P     = (u16*)(ws + 17641472);            // 270,336
  float* cbar  = (float*)(ws + 17911808);          // 524,288
  float* o0    = (float*)(ws + 18436096);          // 32,768
  float* att   = (float*)(ws + 18468864);          // 32,768
  float* h0    = (float*)(ws + 18501632);          // 32,768
  bf16*  f1    = (bf16*)(ws + 18534400);           // 32,768
  float* f2    = (float*)(ws + 18567168);          // 32,768

  build_seq_kernel<<<MPAD_, 256, 0, stream>>>(x, y, cls, sep, px, py, xl, yl, seq);
  qproj_kernel<<<256, 256, 0, stream>>>(cls, Wqkv, bqkv, q0s);
  rproj_kernel<<<dim3(4, 16), 256, 0, stream>>>(Wqkv, q0s, RT_hi, RT_lo);
  scores_kernel<<<130, 256, 0, stream>>>(seq, RT_hi, RT_lo, xl, yl, S);
  softmax_kernel<<<dim3(16, 8), 256, 0, stream>>>(S, xl, yl, P);
  cbar_kernel<<<dim3(16, 8), 256, 0, stream>>>(seq, P, xl, yl, cbar);
  // o0 = Wv . cbar + bv
  gemv8_kernel<1024, 1024, 16384, false, false, false, true>
      <<<256, 256, 0, stream>>>(cbar, Wqkv + (size_t)2048 * 1024, bqkv + 2048, o0);
  // att = Wo . o0 + bo
  gemv8_kernel<1024, 1024, 1024, false, false, false, false>
      <<<256, 256, 0, stream>>>(o0, Wo, bo, att);
  ln_kernel<false><<<B_, 256, 0, stream>>>(cls, att, nullptr, g1, be1, h0);
  // f1 = relu(W1 . h0 + b1)  (bf16)
  gemv8_kernel<1024, 2048, 1024, false, true, true, false>
      <<<512, 256, 0, stream>>>(h0, W1, b1, f1);
  // f2 = W2 . f1 + b2
  gemv8_kernel<2048, 1024, 2048, true, false, false, false>
      <<<256, 256, 0, stream>>>(f1, W2, b2, f2);
  ln_kernel<true><<<B_, 256, 0, stream>>>(nullptr, h0, f2, g2, be2, (float*)d_out);
}